// Round 16
// baseline (134.109 us; speedup 1.0000x reference)
//
#include <hip/hip_runtime.h>

// ---------------------------------------------------------------------------
// MixHop: out = relu([x@W0.T | (Ax)@W1.T | (A^2 x)@W2.T] + b) @ Wout.T + bout
// A = D^{-1/2} (Adj + I) D^{-1/2}, deg over destination (col).
// bf16 feature path (gathers + MFMA), f32 accumulation everywhere.
// Graph build: ATOMIC-FREE two-phase binned CSR ([seg][bin] chunk layout,
// contiguous dumps, LDS atomics only). Prep mega-kernel: binA + cvt_x +
// cvt_w fused via block ranges. binB: exec-masked chunk reads.
// Dense: 64-row tile, Wj LDS-staged, Wout B-frags straight from global
// (L2-hot 16KB); LDS 52KB -> 3 blocks/CU residency; 136-pad (2-way banks).
// ---------------------------------------------------------------------------

#define BPAD 128   // bucket slots per node; deg ~ Poisson(16), P(deg>=128) ~ 0
#define NPB 128    // nodes per bin (bin = dest >> 7)
#define ABINS 512  // allocated bins (N <= 65536)
#define DEPTH 32   // slots per (seg,bin); mean 8, 32 ~ 8.8 sigma
#define NBLKA 256  // Pass A build blocks (= segs)

typedef short bf16x8 __attribute__((ext_vector_type(8)));
typedef float f32x4 __attribute__((ext_vector_type(4)));
typedef float f32x4v __attribute__((ext_vector_type(4)));
typedef unsigned short u16x4 __attribute__((ext_vector_type(4)));

__device__ __forceinline__ ushort f2bf(float f) {
    unsigned u = __float_as_uint(f);
    unsigned r = (u + 0x7fff + ((u >> 16) & 1)) >> 16;  // RNE
    return (ushort)r;
}
__device__ __forceinline__ float bflo(unsigned u) { return __uint_as_float(u << 16); }
__device__ __forceinline__ float bfhi(unsigned u) { return __uint_as_float(u & 0xffff0000u); }

// Fused prep: blocks [0,NBLKA) = Pass A edge binning; [NBLKA, NBLKA+nCvtx) =
// x->bf16 streaming convert; rest = weight convert + repack.
__global__ __launch_bounds__(256) void prep_kernel(
    const int* __restrict__ ei, int* __restrict__ cntA, unsigned* __restrict__ chunk,
    int E,
    const float* __restrict__ x, ushort* __restrict__ xbf, int n4,
    const float* __restrict__ W0, const float* __restrict__ W1,
    const float* __restrict__ W2, const float* __restrict__ Wout,
    ushort* __restrict__ wbf, ushort* __restrict__ woutbf, int nCvtx) {
    int bid = blockIdx.x;
    int tid = threadIdx.x;
    if (bid >= NBLKA) {
        int cb = bid - NBLKA;
        if (cb < nCvtx) {  // streaming cvt_x
            int i = cb * 256 + tid;
            if (i < n4) {
                f32x4v v = __builtin_nontemporal_load((const f32x4v*)x + i);
                u16x4 u = {f2bf(v.x), f2bf(v.y), f2bf(v.z), f2bf(v.w)};
                __builtin_nontemporal_store(u, (u16x4*)xbf + i);
            }
        } else {  // cvt_w: weights -> bf16; woutbf j-major repack
            int i = (cb - nCvtx) * 256 + tid;
            if (i < 16384) wbf[i] = f2bf(W0[i]);
            else if (i < 32768) wbf[i] = f2bf(W1[i - 16384]);
            else if (i < 49152) wbf[i] = f2bf(W2[i - 32768]);
            else if (i < 73728) {
                int t = i - 49152;          // o*384 + c384
                int o = t / 384, c384 = t % 384;
                int j = c384 >> 7, cj = c384 & 127;
                woutbf[j * 8192 + o * 128 + cj] = f2bf(Wout[t]);
            }
        }
        return;
    }
    // ---- Pass A: bin edges by dest>>7 into per-bin LDS buffers ----
    __shared__ unsigned lbuf[ABINS][DEPTH];  // 64KB
    __shared__ int lcnt[ABINS];
    for (int b = tid; b < ABINS; b += 256) lcnt[b] = 0;
    __syncthreads();
    int is64 = 1;
#pragma unroll
    for (int k = 0; k < 8; k++) is64 &= (ei[2 * k + 1] == 0);
    int stride = NBLKA * 256;
    for (int e = bid * 256 + tid; e < E; e += stride) {
        int c, r;
        if (is64) {
            c = ((const int2*)ei)[(size_t)E + e].x;
            r = ((const int2*)ei)[e].x;
        } else {
            c = ei[(size_t)E + e];
            r = ei[e];
        }
        int bin = c >> 7;
        unsigned entry = ((unsigned)(c & 127) << 16) | (unsigned)r;
        int pos = atomicAdd(&lcnt[bin], 1);          // LDS atomic
        if (pos < DEPTH) lbuf[bin][pos] = entry;     // overflow ~ 1e-11
    }
    __syncthreads();
    // dump whole staging array: contiguous, fully coalesced
    unsigned* dst = chunk + (size_t)bid * ABINS * DEPTH;
    const unsigned* src = (const unsigned*)lbuf;
    for (int s = tid; s < ABINS * DEPTH; s += 256) dst[s] = src[s];
    for (int b = tid; b < ABINS; b += 256)
        cntA[bid * ABINS + b] = min(lcnt[b], DEPTH);
}

// Pass B: one 512-thread block per 128-node bin. Exec-masked sweep of the
// bin's NBLKA*DEPTH entry slots, LDS-atomic append, cnt/dis, coalesced out.
__global__ __launch_bounds__(512) void binB_kernel(
    const int* __restrict__ cntA, const unsigned* __restrict__ chunk,
    int* __restrict__ cnt, float* __restrict__ dis,
    ushort* __restrict__ bucket, int N) {
    __shared__ ushort lbkt[NPB][BPAD];  // 32KB
    __shared__ int lcnt[NPB];
    __shared__ int mcnt[NBLKA];
    int b = blockIdx.x;
    int tid = threadIdx.x;
    for (int i = tid; i < NPB; i += 512) lcnt[i] = 0;
    for (int i = tid; i < NBLKA; i += 512) mcnt[i] = cntA[i * ABINS + b];
    __syncthreads();
    for (int i = tid; i < NBLKA * DEPTH; i += 512) {
        int seg = i >> 5;       // DEPTH = 32
        int slot = i & 31;
        if (slot < mcnt[seg]) {  // mask BEFORE load: only valid lines fetched
            unsigned entry = chunk[(size_t)seg * ABINS * DEPTH + (size_t)b * DEPTH + slot];
            int cl = entry >> 16;
            int pos = atomicAdd(&lcnt[cl], 1);       // LDS atomic
            if (pos < BPAD) lbkt[cl][pos] = (ushort)entry;
        }
    }
    __syncthreads();
    int node0 = b * NPB;
    for (int i = tid; i < NPB; i += 512) {
        int node = node0 + i;
        if (node < N) {
            cnt[node] = lcnt[i];
            dis[node] = rsqrtf(1.0f + (float)lcnt[i]);  // +1 self loop
        }
    }
    // stream bucket slice: 16 uint4 per node row (256B), fully coalesced
    const uint4* src = (const uint4*)lbkt;
    uint4* dst = (uint4*)(bucket + (size_t)node0 * BPAD);
    for (int i = tid; i < NPB * BPAD / 8; i += 512) {  // 2048 uint4
        int row = node0 + (i >> 4);
        if (row < N) dst[i] = src[i];
    }
}

// One wave per destination node; 64 lanes x (2 bf16) = 128 features.
// node/deg/bucket reads wave-uniform -> scalar loads (packed ushort pairs).
__global__ __launch_bounds__(256) void prop_kernel(
    const ushort* __restrict__ in, ushort* __restrict__ out,
    const int* __restrict__ cnt, const ushort* __restrict__ bucket,
    const float* __restrict__ dis, int N) {
    int node = __builtin_amdgcn_readfirstlane(blockIdx.x * 4 + (threadIdx.x >> 6));
    if (node >= N) return;
    int lane = threadIdx.x & 63;

    float dn = dis[node];
    unsigned v = ((const unsigned*)(in + (size_t)node * 128))[lane];
    float self = dn * dn;
    float ax = self * bflo(v), ay = self * bfhi(v);

    int deg = cnt[node];
    if (deg > BPAD) deg = BPAD;
    const unsigned* bp32 = (const unsigned*)(bucket + (size_t)node * BPAD);
    int e = 0;
    for (; e + 7 < deg; e += 8) {  // e stays even
        unsigned pk[4];
#pragma unroll
        for (int q = 0; q < 4; q++) pk[q] = bp32[(e >> 1) + q];
        int r[8];
#pragma unroll
        for (int q = 0; q < 4; q++) {
            r[2 * q] = pk[q] & 0xffff;
            r[2 * q + 1] = pk[q] >> 16;
        }
        unsigned u[8];
        float w[8];
#pragma unroll
        for (int q = 0; q < 8; q++) u[q] = ((const unsigned*)(in + (size_t)r[q] * 128))[lane];
#pragma unroll
        for (int q = 0; q < 8; q++) w[q] = dn * dis[r[q]];
#pragma unroll
        for (int q = 0; q < 8; q++) {
            ax = fmaf(w[q], bflo(u[q]), ax);
            ay = fmaf(w[q], bfhi(u[q]), ay);
        }
    }
    for (; e + 3 < deg; e += 4) {  // e stays even
        unsigned pk0 = bp32[(e >> 1) + 0], pk1 = bp32[(e >> 1) + 1];
        int r0 = pk0 & 0xffff, r1 = pk0 >> 16;
        int r2 = pk1 & 0xffff, r3 = pk1 >> 16;
        float w0 = dn * dis[r0], w1 = dn * dis[r1];
        float w2 = dn * dis[r2], w3 = dn * dis[r3];
        unsigned u0 = ((const unsigned*)(in + (size_t)r0 * 128))[lane];
        unsigned u1 = ((const unsigned*)(in + (size_t)r1 * 128))[lane];
        unsigned u2 = ((const unsigned*)(in + (size_t)r2 * 128))[lane];
        unsigned u3 = ((const unsigned*)(in + (size_t)r3 * 128))[lane];
        ax = fmaf(w0, bflo(u0), ax); ay = fmaf(w0, bfhi(u0), ay);
        ax = fmaf(w1, bflo(u1), ax); ay = fmaf(w1, bfhi(u1), ay);
        ax = fmaf(w2, bflo(u2), ax); ay = fmaf(w2, bfhi(u2), ay);
        ax = fmaf(w3, bflo(u3), ax); ay = fmaf(w3, bfhi(u3), ay);
    }
    for (; e < deg; e++) {
        int r0 = bucket[(size_t)node * BPAD + e];
        float w0 = dn * dis[r0];
        unsigned u0 = ((const unsigned*)(in + (size_t)r0 * 128))[lane];
        ax = fmaf(w0, bflo(u0), ax); ay = fmaf(w0, bfhi(u0), ay);
    }
    unsigned res = (unsigned)f2bf(ax) | ((unsigned)f2bf(ay) << 16);
    ((unsigned*)(out + (size_t)node * 128))[lane] = res;
}

// Fused dense via bf16 MFMA. 64-row tile / 4 waves. Wj LDS-staged per hop;
// Wout B-frags read straight from global (16KB j-slice, L2-hot — ~75MB total
// L2 reads across the grid, trivial). LDS 52KB -> 3 blocks/CU residency.
// 136-pad: row stride 272B = 68 dwords = +4 banks/row -> 2-way (free).
__global__ __launch_bounds__(256) void dense_mfma_kernel(
    const ushort* __restrict__ x, const ushort* __restrict__ ax, const ushort* __restrict__ a2x,
    const ushort* __restrict__ wbf,    // [3][128][128] bf16
    const ushort* __restrict__ woutbf, // [3][64][128] bf16 (j-major)
    const float* __restrict__ b0, const float* __restrict__ b1, const float* __restrict__ b2,
    const float* __restrict__ bout,
    float* __restrict__ out, int N) {
    __shared__ ushort wjlds[128][136];  // hop weight, 34.8KB
    __shared__ ushort hts[4][16][136];  // per-wave H slab, 17.4KB
    int tid = threadIdx.x;
    int lane = tid & 63;
    int wid = __builtin_amdgcn_readfirstlane(tid >> 6);
    int l15 = lane & 15;
    int kb = lane >> 4;  // 0..3
    int row = blockIdx.x * 64 + wid * 16 + l15;  // this lane's A row
    int rowc = row < N ? row : N - 1;            // clamp (stores guarded)
    int orow = blockIdx.x * 64 + wid * 16 + kb * 4;

    const ushort* ins[3] = {x, ax, a2x};
    const float* bs[3] = {b0, b1, b2};

    // staging assignment: thread handles 16B-chunks tid + i*256
    int srow = tid >> 4;       // 0..15 base row group
    int sc16 = tid & 15;       // chunk-in-row

    f32x4 oacc[4];
#pragma unroll
    for (int n2 = 0; n2 < 4; n2++) {
        float b = bout[n2 * 16 + l15];
        oacc[n2] = (f32x4){b, b, b, b};
    }

#pragma unroll
    for (int j = 0; j < 3; j++) {
        const ushort* in = ins[j];
        const ushort* wj = wbf + j * 16384;
        const ushort* wo = woutbf + j * 8192;
        const float* bj = bs[j];

        // A-frags straight from global (4 independent 16B loads)
        bf16x8 a[4];
#pragma unroll
        for (int k = 0; k < 4; k++)
            a[k] = *(const bf16x8*)&in[(size_t)rowc * 128 + k * 32 + kb * 8];

        // issue Wj stage loads (hide latency under prev hop + barrier)
        bf16x8 wreg[8];
#pragma unroll
        for (int i = 0; i < 8; i++)
            wreg[i] = *(const bf16x8*)&wj[(srow + i * 16) * 128 + sc16 * 8];

        float bv[8];
#pragma unroll
        for (int n = 0; n < 8; n++) bv[n] = bj[n * 16 + l15];

        __syncthreads();  // prev hop's weight-LDS readers done
#pragma unroll
        for (int i = 0; i < 8; i++)
            *(bf16x8*)&wjlds[srow + i * 16][sc16 * 8] = wreg[i];
        __syncthreads();  // staging visible

        // H = relu(A @ Wj.T + bj), B-frags from LDS
#pragma unroll
        for (int n = 0; n < 8; n++) {
            f32x4 h = (f32x4){bv[n], bv[n], bv[n], bv[n]};
#pragma unroll
            for (int k = 0; k < 4; k++) {
                bf16x8 b = *(const bf16x8*)&wjlds[n * 16 + l15][k * 32 + kb * 8];
                h = __builtin_amdgcn_mfma_f32_16x16x32_bf16(a[k], b, h, 0, 0, 0);
            }
#pragma unroll
            for (int r = 0; r < 4; r++)
                hts[wid][kb * 4 + r][n * 16 + l15] = f2bf(fmaxf(h[r], 0.f));
        }

        // A2 from own slab; OUT += H @ WoutJ.T (B-frags straight from L2)
        bf16x8 a2[4];
#pragma unroll
        for (int k = 0; k < 4; k++)
            a2[k] = *(const bf16x8*)&hts[wid][l15][k * 32 + kb * 8];
#pragma unroll
        for (int n2 = 0; n2 < 4; n2++) {
#pragma unroll
            for (int k = 0; k < 4; k++) {
                bf16x8 b2 = *(const bf16x8*)&wo[(n2 * 16 + l15) * 128 + k * 32 + kb * 8];
                oacc[n2] = __builtin_amdgcn_mfma_f32_16x16x32_bf16(a2[k], b2, oacc[n2], 0, 0, 0);
            }
        }
    }

#pragma unroll
    for (int n2 = 0; n2 < 4; n2++) {
#pragma unroll
        for (int r = 0; r < 4; r++) {
            int rw = orow + r;
            if (rw < N) out[(size_t)rw * 64 + n2 * 16 + l15] = oacc[n2][r];
        }
    }
}

extern "C" void kernel_launch(void* const* d_in, const int* in_sizes, int n_in,
                              void* d_out, int out_size, void* d_ws, size_t ws_size,
                              hipStream_t stream) {
    const float* x = (const float*)d_in[0];
    const int* ei = (const int*)d_in[1];
    const float* W0 = (const float*)d_in[2];
    const float* b0 = (const float*)d_in[3];
    const float* W1 = (const float*)d_in[4];
    const float* b1 = (const float*)d_in[5];
    const float* W2 = (const float*)d_in[6];
    const float* b2 = (const float*)d_in[7];
    const float* Wout = (const float*)d_in[8];
    const float* bout = (const float*)d_in[9];
    float* out = (float*)d_out;

    int N = in_sizes[0] / 128;
    int E = in_sizes[1] / 2;
    int nbins = (N + NPB - 1) / NPB;

    size_t off = 0;
    auto alloc = [&](size_t bytes) -> void* {
        void* p = (char*)d_ws + off;
        off += (bytes + 255) & ~(size_t)255;
        return p;
    };
    int* cnt = (int*)alloc((size_t)N * 4);
    float* dis = (float*)alloc((size_t)N * 4);
    int* cntA = (int*)alloc((size_t)NBLKA * ABINS * 4);                     // 512KB
    unsigned* chunk = (unsigned*)alloc((size_t)NBLKA * ABINS * DEPTH * 4);  // 16MB
    ushort* bucket = (ushort*)alloc((size_t)N * BPAD * 2);
    ushort* xbf = (ushort*)alloc((size_t)N * 128 * 2);
    ushort* axbf = (ushort*)alloc((size_t)N * 128 * 2);
    ushort* a2xbf = (ushort*)alloc((size_t)N * 128 * 2);
    ushort* wbf = (ushort*)alloc((size_t)3 * 16384 * 2);
    ushort* woutbf = (ushort*)alloc((size_t)24576 * 2);
    (void)ws_size;

    int n4 = N * 32;  // float4 count of x
    int nCvtx = (n4 + 255) / 256;
    int nCvtw = 288;

    prep_kernel<<<NBLKA + nCvtx + nCvtw, 256, 0, stream>>>(
        ei, cntA, chunk, E, x, xbf, n4, W0, W1, W2, Wout, wbf, woutbf, nCvtx);
    binB_kernel<<<nbins, 512, 0, stream>>>(cntA, chunk, cnt, dis, bucket, N);
    prop_kernel<<<(N + 3) / 4, 256, 0, stream>>>(xbf, axbf, cnt, bucket, dis, N);
    prop_kernel<<<(N + 3) / 4, 256, 0, stream>>>(axbf, a2xbf, cnt, bucket, dis, N);
    dense_mfma_kernel<<<(N + 63) / 64, 256, 0, stream>>>(xbf, axbf, a2xbf, wbf, woutbf,
                                                         b0, b1, b2, bout, out, N);
}

// Round 17
// 120.765 us; speedup vs baseline: 1.1105x; 1.1105x over previous
//
#include <hip/hip_runtime.h>

// ---------------------------------------------------------------------------
// MixHop: out = relu([x@W0.T | (Ax)@W1.T | (A^2 x)@W2.T] + b) @ Wout.T + bout
// A = D^{-1/2} (Adj + I) D^{-1/2}, deg over destination (col).
// bf16 feature path (gathers + MFMA), f32 accumulation everywhere.
// Graph build: ATOMIC-FREE two-phase binned CSR ([seg][bin] chunk layout,
// contiguous dumps, LDS atomics only). Prep mega-kernel: binA + cvt_x +
// cvt_w fused via block ranges (build blocks dispatch first).
// binB: conditional (exec-masked) chunk reads — only valid slots fetched.
// Dense: 128-row blocks; per wave two 16-row groups share one LDS weight
// stage; BOTH Wj and Wout LDS-staged (per-wave L2 weight re-reads are the
// dominant dense cost — confirmed R4/R5/R16); per-wave H slab; 2 barriers/hop.
// ---------------------------------------------------------------------------

#define BPAD 128   // bucket slots per node; deg ~ Poisson(16), P(deg>=128) ~ 0
#define NPB 128    // nodes per bin (bin = dest >> 7)
#define ABINS 512  // allocated bins (N <= 65536)
#define DEPTH 32   // slots per (seg,bin); mean 8, 32 ~ 8.8 sigma
#define NBLKA 256  // Pass A build blocks (= segs)

typedef short bf16x8 __attribute__((ext_vector_type(8)));
typedef float f32x4 __attribute__((ext_vector_type(4)));
typedef float f32x4v __attribute__((ext_vector_type(4)));
typedef unsigned short u16x4 __attribute__((ext_vector_type(4)));

__device__ __forceinline__ ushort f2bf(float f) {
    unsigned u = __float_as_uint(f);
    unsigned r = (u + 0x7fff + ((u >> 16) & 1)) >> 16;  // RNE
    return (ushort)r;
}
__device__ __forceinline__ float bflo(unsigned u) { return __uint_as_float(u << 16); }
__device__ __forceinline__ float bfhi(unsigned u) { return __uint_as_float(u & 0xffff0000u); }

// Fused prep: blocks [0,NBLKA) = Pass A edge binning; [NBLKA, NBLKA+nCvtx) =
// x->bf16 streaming convert; rest = weight convert + repack.
// is64 detection inlined per build block (int64 high words are 0 since
// indices < 50000; misdetect needs 8 random int32 rows all 0: P ~ 0).
__global__ __launch_bounds__(256) void prep_kernel(
    const int* __restrict__ ei, int* __restrict__ cntA, unsigned* __restrict__ chunk,
    int E,
    const float* __restrict__ x, ushort* __restrict__ xbf, int n4,
    const float* __restrict__ W0, const float* __restrict__ W1,
    const float* __restrict__ W2, const float* __restrict__ Wout,
    ushort* __restrict__ wbf, ushort* __restrict__ woutbf, int nCvtx) {
    int bid = blockIdx.x;
    int tid = threadIdx.x;
    if (bid >= NBLKA) {
        int cb = bid - NBLKA;
        if (cb < nCvtx) {  // streaming cvt_x
            int i = cb * 256 + tid;
            if (i < n4) {
                f32x4v v = __builtin_nontemporal_load((const f32x4v*)x + i);
                u16x4 u = {f2bf(v.x), f2bf(v.y), f2bf(v.z), f2bf(v.w)};
                __builtin_nontemporal_store(u, (u16x4*)xbf + i);
            }
        } else {  // cvt_w: weights -> bf16; woutbf j-major repack
            int i = (cb - nCvtx) * 256 + tid;
            if (i < 16384) wbf[i] = f2bf(W0[i]);
            else if (i < 32768) wbf[i] = f2bf(W1[i - 16384]);
            else if (i < 49152) wbf[i] = f2bf(W2[i - 32768]);
            else if (i < 73728) {
                int t = i - 49152;          // o*384 + c384
                int o = t / 384, c384 = t % 384;
                int j = c384 >> 7, cj = c384 & 127;
                woutbf[j * 8192 + o * 128 + cj] = f2bf(Wout[t]);
            }
        }
        return;
    }
    // ---- Pass A: bin edges by dest>>7 into per-bin LDS buffers ----
    __shared__ unsigned lbuf[ABINS][DEPTH];  // 64KB
    __shared__ int lcnt[ABINS];
    for (int b = tid; b < ABINS; b += 256) lcnt[b] = 0;
    __syncthreads();
    int is64 = 1;
#pragma unroll
    for (int k = 0; k < 8; k++) is64 &= (ei[2 * k + 1] == 0);
    int stride = NBLKA * 256;
    for (int e = bid * 256 + tid; e < E; e += stride) {
        int c, r;
        if (is64) {
            c = ((const int2*)ei)[(size_t)E + e].x;
            r = ((const int2*)ei)[e].x;
        } else {
            c = ei[(size_t)E + e];
            r = ei[e];
        }
        int bin = c >> 7;
        unsigned entry = ((unsigned)(c & 127) << 16) | (unsigned)r;
        int pos = atomicAdd(&lcnt[bin], 1);          // LDS atomic
        if (pos < DEPTH) lbuf[bin][pos] = entry;     // overflow ~ 1e-11
    }
    __syncthreads();
    // dump whole staging array: contiguous, fully coalesced
    unsigned* dst = chunk + (size_t)bid * ABINS * DEPTH;
    const unsigned* src = (const unsigned*)lbuf;
    for (int s = tid; s < ABINS * DEPTH; s += 256) dst[s] = src[s];
    for (int b = tid; b < ABINS; b += 256)
        cntA[bid * ABINS + b] = min(lcnt[b], DEPTH);
}

// Pass B: one 512-thread block per 128-node bin. Exec-masked sweep of the
// bin's NBLKA*DEPTH entry slots (only valid-slot lines fetched), LDS-atomic
// append into the bin's bucket slice, cnt/dis, coalesced stream-out.
__global__ __launch_bounds__(512) void binB_kernel(
    const int* __restrict__ cntA, const unsigned* __restrict__ chunk,
    int* __restrict__ cnt, float* __restrict__ dis,
    ushort* __restrict__ bucket, int N) {
    __shared__ ushort lbkt[NPB][BPAD];  // 32KB
    __shared__ int lcnt[NPB];
    __shared__ int mcnt[NBLKA];
    int b = blockIdx.x;
    int tid = threadIdx.x;
    for (int i = tid; i < NPB; i += 512) lcnt[i] = 0;
    for (int i = tid; i < NBLKA; i += 512) mcnt[i] = cntA[i * ABINS + b];
    __syncthreads();
    for (int i = tid; i < NBLKA * DEPTH; i += 512) {
        int seg = i >> 5;       // DEPTH = 32
        int slot = i & 31;
        if (slot < mcnt[seg]) {  // mask BEFORE load: only valid lines fetched
            unsigned entry = chunk[(size_t)seg * ABINS * DEPTH + (size_t)b * DEPTH + slot];
            int cl = entry >> 16;
            int pos = atomicAdd(&lcnt[cl], 1);       // LDS atomic
            if (pos < BPAD) lbkt[cl][pos] = (ushort)entry;
        }
    }
    __syncthreads();
    int node0 = b * NPB;
    for (int i = tid; i < NPB; i += 512) {
        int node = node0 + i;
        if (node < N) {
            cnt[node] = lcnt[i];
            dis[node] = rsqrtf(1.0f + (float)lcnt[i]);  // +1 self loop
        }
    }
    // stream bucket slice: 16 uint4 per node row (256B), fully coalesced
    const uint4* src = (const uint4*)lbkt;
    uint4* dst = (uint4*)(bucket + (size_t)node0 * BPAD);
    for (int i = tid; i < NPB * BPAD / 8; i += 512) {  // 2048 uint4
        int row = node0 + (i >> 4);
        if (row < N) dst[i] = src[i];
    }
}

// One wave per destination node; 64 lanes x (2 bf16) = 128 features.
// node/deg/bucket reads wave-uniform -> scalar loads (packed ushort pairs).
__global__ __launch_bounds__(256) void prop_kernel(
    const ushort* __restrict__ in, ushort* __restrict__ out,
    const int* __restrict__ cnt, const ushort* __restrict__ bucket,
    const float* __restrict__ dis, int N) {
    int node = __builtin_amdgcn_readfirstlane(blockIdx.x * 4 + (threadIdx.x >> 6));
    if (node >= N) return;
    int lane = threadIdx.x & 63;

    float dn = dis[node];
    unsigned v = ((const unsigned*)(in + (size_t)node * 128))[lane];
    float self = dn * dn;
    float ax = self * bflo(v), ay = self * bfhi(v);

    int deg = cnt[node];
    if (deg > BPAD) deg = BPAD;
    const unsigned* bp32 = (const unsigned*)(bucket + (size_t)node * BPAD);
    int e = 0;
    for (; e + 7 < deg; e += 8) {  // e stays even
        unsigned pk[4];
#pragma unroll
        for (int q = 0; q < 4; q++) pk[q] = bp32[(e >> 1) + q];
        int r[8];
#pragma unroll
        for (int q = 0; q < 4; q++) {
            r[2 * q] = pk[q] & 0xffff;
            r[2 * q + 1] = pk[q] >> 16;
        }
        unsigned u[8];
        float w[8];
#pragma unroll
        for (int q = 0; q < 8; q++) u[q] = ((const unsigned*)(in + (size_t)r[q] * 128))[lane];
#pragma unroll
        for (int q = 0; q < 8; q++) w[q] = dn * dis[r[q]];
#pragma unroll
        for (int q = 0; q < 8; q++) {
            ax = fmaf(w[q], bflo(u[q]), ax);
            ay = fmaf(w[q], bfhi(u[q]), ay);
        }
    }
    for (; e + 3 < deg; e += 4) {  // e stays even
        unsigned pk0 = bp32[(e >> 1) + 0], pk1 = bp32[(e >> 1) + 1];
        int r0 = pk0 & 0xffff, r1 = pk0 >> 16;
        int r2 = pk1 & 0xffff, r3 = pk1 >> 16;
        float w0 = dn * dis[r0], w1 = dn * dis[r1];
        float w2 = dn * dis[r2], w3 = dn * dis[r3];
        unsigned u0 = ((const unsigned*)(in + (size_t)r0 * 128))[lane];
        unsigned u1 = ((const unsigned*)(in + (size_t)r1 * 128))[lane];
        unsigned u2 = ((const unsigned*)(in + (size_t)r2 * 128))[lane];
        unsigned u3 = ((const unsigned*)(in + (size_t)r3 * 128))[lane];
        ax = fmaf(w0, bflo(u0), ax); ay = fmaf(w0, bfhi(u0), ay);
        ax = fmaf(w1, bflo(u1), ax); ay = fmaf(w1, bfhi(u1), ay);
        ax = fmaf(w2, bflo(u2), ax); ay = fmaf(w2, bfhi(u2), ay);
        ax = fmaf(w3, bflo(u3), ax); ay = fmaf(w3, bfhi(u3), ay);
    }
    for (; e < deg; e++) {
        int r0 = bucket[(size_t)node * BPAD + e];
        float w0 = dn * dis[r0];
        unsigned u0 = ((const unsigned*)(in + (size_t)r0 * 128))[lane];
        ax = fmaf(w0, bflo(u0), ax); ay = fmaf(w0, bfhi(u0), ay);
    }
    unsigned res = (unsigned)f2bf(ax) | ((unsigned)f2bf(ay) << 16);
    ((unsigned*)(out + (size_t)node * 128))[lane] = res;
}

// Fused dense via bf16 MFMA, weights LDS-staged per hop.
// Block = 256 thr / 4 waves, 128-row tile: each wave owns 32 rows as TWO
// 16-row groups processed sequentially against ONE weight stage.
// LDS 72KB -> 2 blk/CU. Rows padded to 144 ushorts (288B, 16B-aligned).
__global__ __launch_bounds__(256) void dense_mfma_kernel(
    const ushort* __restrict__ x, const ushort* __restrict__ ax, const ushort* __restrict__ a2x,
    const ushort* __restrict__ wbf,    // [3][128][128] bf16
    const ushort* __restrict__ woutbf, // [3][64][128] bf16 (j-major)
    const float* __restrict__ b0, const float* __restrict__ b1, const float* __restrict__ b2,
    const float* __restrict__ bout,
    float* __restrict__ out, int N) {
    __shared__ ushort wjlds[128][144];  // hop weight, 36KB
    __shared__ ushort wolds[64][144];   // hop out-weight slice, 18KB
    __shared__ ushort hts[4][16][144];  // per-wave H slab (reused x2), 18KB
    int tid = threadIdx.x;
    int lane = tid & 63;
    int wid = __builtin_amdgcn_readfirstlane(tid >> 6);
    int l15 = lane & 15;
    int kb = lane >> 4;  // 0..3
    int rowbase = blockIdx.x * 128 + wid * 32;
    int row0 = rowbase + l15;            // group-0 A row
    int row1 = rowbase + 16 + l15;       // group-1 A row
    int row0c = row0 < N ? row0 : N - 1; // clamp (stores guarded)
    int row1c = row1 < N ? row1 : N - 1;
    int orow0 = rowbase + kb * 4;
    int orow1 = rowbase + 16 + kb * 4;

    const ushort* ins[3] = {x, ax, a2x};
    const float* bs[3] = {b0, b1, b2};

    // staging assignment: thread handles 16B-chunks tid + i*256
    int srow = tid >> 4;       // 0..15 base row group
    int sc16 = tid & 15;       // chunk-in-row

    f32x4 oacc0[4], oacc1[4];
#pragma unroll
    for (int n2 = 0; n2 < 4; n2++) {
        float b = bout[n2 * 16 + l15];
        oacc0[n2] = (f32x4){b, b, b, b};
        oacc1[n2] = (f32x4){b, b, b, b};
    }

#pragma unroll
    for (int j = 0; j < 3; j++) {
        const ushort* in = ins[j];
        const ushort* wj = wbf + j * 16384;
        const ushort* wo = woutbf + j * 8192;
        const float* bj = bs[j];

        // A-frags straight from global (8 independent 16B loads, 2 groups)
        bf16x8 a0[4], a1[4];
#pragma unroll
        for (int k = 0; k < 4; k++) {
            a0[k] = *(const bf16x8*)&in[(size_t)row0c * 128 + k * 32 + kb * 8];
            a1[k] = *(const bf16x8*)&in[(size_t)row1c * 128 + k * 32 + kb * 8];
        }

        // issue weight stage loads (hide latency under prev hop + barrier)
        bf16x8 wreg[8], woreg[4];
#pragma unroll
        for (int i = 0; i < 8; i++)
            wreg[i] = *(const bf16x8*)&wj[(srow + i * 16) * 128 + sc16 * 8];
#pragma unroll
        for (int i = 0; i < 4; i++)
            woreg[i] = *(const bf16x8*)&wo[(srow + i * 16) * 128 + sc16 * 8];

        float bv[8];
#pragma unroll
        for (int n = 0; n < 8; n++) bv[n] = bj[n * 16 + l15];

        __syncthreads();  // prev hop's weight-LDS readers done
#pragma unroll
        for (int i = 0; i < 8; i++)
            *(bf16x8*)&wjlds[srow + i * 16][sc16 * 8] = wreg[i];
#pragma unroll
        for (int i = 0; i < 4; i++)
            *(bf16x8*)&wolds[srow + i * 16][sc16 * 8] = woreg[i];
        __syncthreads();  // staging visible

        // ---- group 0: H = relu(A0 @ Wj.T + bj); OUT0 += H @ WoutJ.T ----
#pragma unroll
        for (int n = 0; n < 8; n++) {
            f32x4 h = (f32x4){bv[n], bv[n], bv[n], bv[n]};
#pragma unroll
            for (int k = 0; k < 4; k++) {
                bf16x8 b = *(const bf16x8*)&wjlds[n * 16 + l15][k * 32 + kb * 8];
                h = __builtin_amdgcn_mfma_f32_16x16x32_bf16(a0[k], b, h, 0, 0, 0);
            }
#pragma unroll
            for (int r = 0; r < 4; r++)
                hts[wid][kb * 4 + r][n * 16 + l15] = f2bf(fmaxf(h[r], 0.f));
        }
        {
            bf16x8 a2[4];
#pragma unroll
            for (int k = 0; k < 4; k++)
                a2[k] = *(const bf16x8*)&hts[wid][l15][k * 32 + kb * 8];
#pragma unroll
            for (int n2 = 0; n2 < 4; n2++) {
#pragma unroll
                for (int k = 0; k < 4; k++) {
                    bf16x8 b2 = *(const bf16x8*)&wolds[n2 * 16 + l15][k * 32 + kb * 8];
                    oacc0[n2] = __builtin_amdgcn_mfma_f32_16x16x32_bf16(a2[k], b2, oacc0[n2], 0, 0, 0);
                }
            }
        }

        // ---- group 1: reuse the same wave-private H slab ----
#pragma unroll
        for (int n = 0; n < 8; n++) {
            f32x4 h = (f32x4){bv[n], bv[n], bv[n], bv[n]};
#pragma unroll
            for (int k = 0; k < 4; k++) {
                bf16x8 b = *(const bf16x8*)&wjlds[n * 16 + l15][k * 32 + kb * 8];
                h = __builtin_amdgcn_mfma_f32_16x16x32_bf16(a1[k], b, h, 0, 0, 0);
            }
#pragma unroll
            for (int r = 0; r < 4; r++)
                hts[wid][kb * 4 + r][n * 16 + l15] = f2bf(fmaxf(h[r], 0.f));
        }
        {
            bf16x8 a2[4];
#pragma unroll
            for (int k = 0; k < 4; k++)
                a2[k] = *(const bf16x8*)&hts[wid][l15][k * 32 + kb * 8];
#pragma unroll
            for (int n2 = 0; n2 < 4; n2++) {
#pragma unroll
                for (int k = 0; k < 4; k++) {
                    bf16x8 b2 = *(const bf16x8*)&wolds[n2 * 16 + l15][k * 32 + kb * 8];
                    oacc1[n2] = __builtin_amdgcn_mfma_f32_16x16x32_bf16(a2[k], b2, oacc1[n2], 0, 0, 0);
                }
            }
        }
    }

#pragma unroll
    for (int n2 = 0; n2 < 4; n2++) {
#pragma unroll
        for (int r = 0; r < 4; r++) {
            int rw0 = orow0 + r;
            int rw1 = orow1 + r;
            if (rw0 < N) out[(size_t)rw0 * 64 + n2 * 16 + l15] = oacc0[n2][r];
            if (rw1 < N) out[(size_t)rw1 * 64 + n2 * 16 + l15] = oacc1[n2][r];
        }
    }
}

extern "C" void kernel_launch(void* const* d_in, const int* in_sizes, int n_in,
                              void* d_out, int out_size, void* d_ws, size_t ws_size,
                              hipStream_t stream) {
    const float* x = (const float*)d_in[0];
    const int* ei = (const int*)d_in[1];
    const float* W0 = (const float*)d_in[2];
    const float* b0 = (const float*)d_in[3];
    const float* W1 = (const float*)d_in[4];
    const float* b1 = (const float*)d_in[5];
    const float* W2 = (const float*)d_in[6];
    const float* b2 = (const float*)d_in[7];
    const float* Wout = (const float*)d_in[8];
    const float* bout = (const float*)d_in[9];
    float* out = (float*)d_out;

    int N = in_sizes[0] / 128;
    int E = in_sizes[1] / 2;
    int nbins = (N + NPB - 1) / NPB;

    size_t off = 0;
    auto alloc = [&](size_t bytes) -> void* {
        void* p = (char*)d_ws + off;
        off += (bytes + 255) & ~(size_t)255;
        return p;
    };
    int* cnt = (int*)alloc((size_t)N * 4);
    float* dis = (float*)alloc((size_t)N * 4);
    int* cntA = (int*)alloc((size_t)NBLKA * ABINS * 4);                     // 512KB
    unsigned* chunk = (unsigned*)alloc((size_t)NBLKA * ABINS * DEPTH * 4);  // 16MB
    ushort* bucket = (ushort*)alloc((size_t)N * BPAD * 2);
    ushort* xbf = (ushort*)alloc((size_t)N * 128 * 2);
    ushort* axbf = (ushort*)alloc((size_t)N * 128 * 2);
    ushort* a2xbf = (ushort*)alloc((size_t)N * 128 * 2);
    ushort* wbf = (ushort*)alloc((size_t)3 * 16384 * 2);
    ushort* woutbf = (ushort*)alloc((size_t)24576 * 2);
    (void)ws_size;

    int n4 = N * 32;  // float4 count of x
    int nCvtx = (n4 + 255) / 256;
    int nCvtw = 288;

    prep_kernel<<<NBLKA + nCvtx + nCvtw, 256, 0, stream>>>(
        ei, cntA, chunk, E, x, xbf, n4, W0, W1, W2, Wout, wbf, woutbf, nCvtx);
    binB_kernel<<<nbins, 512, 0, stream>>>(cntA, chunk, cnt, dis, bucket, N);
    prop_kernel<<<(N + 3) / 4, 256, 0, stream>>>(xbf, axbf, cnt, bucket, dis, N);
    prop_kernel<<<(N + 3) / 4, 256, 0, stream>>>(axbf, a2xbf, cnt, bucket, dis, N);
    dense_mfma_kernel<<<(N + 127) / 128, 256, 0, stream>>>(xbf, axbf, a2xbf, wbf, woutbf,
                                                           b0, b1, b2, bout, out, N);
}